// Round 5
// baseline (174.471 us; speedup 1.0000x reference)
//
#include <hip/hip_runtime.h>
#include <hip/hip_bf16.h>

// Sizes (fixed by the reference)
#define BB 64
#define AA 128
#define FF 32
#define HH 64

typedef float float4v __attribute__((ext_vector_type(4)));

// ws layout (float offsets)
#define OFF_HIP   0
#define OFF_HJ    524288
#define OFF_BU    1048576
#define OFF_UTIL  1056768
#define OFF_W2T   1064960
#define OFF_JLIST 1069056
#define OFF_JCNT  1077248

// ---------------- Kernel 1: per-(b,a) features + j-lists + W2 transpose ----
__global__ __launch_bounds__(64)
void ddc_features(const float* __restrict__ X, const int* __restrict__ mask,
                  const float* __restrict__ bW1, const float* __restrict__ bb1,
                  const float* __restrict__ bW2, const float* __restrict__ bb2,
                  const float* __restrict__ bW3, const float* __restrict__ bb3,
                  const float* __restrict__ pW1, const float* __restrict__ pb1,
                  const float* __restrict__ pW2,
                  float* __restrict__ hi_p, float* __restrict__ hj,
                  float* __restrict__ base_u, float* __restrict__ W2t,
                  int* __restrict__ jlist, int* __restrict__ jcnt) {
    const int a = blockIdx.x, b = blockIdx.y, lane = threadIdx.x;
    const int row = b * AA + a;

    // X row is wave-uniform -> scalar loads
    const float* __restrict__ x = X + row * FF;
    float xr[FF];
#pragma unroll
    for (int f = 0; f < FF; ++f) xr[f] = x[f];

    float vhi = pb1[lane];      // fold pair_b1 into hi
    float vhj = 0.f;
    float v1  = bb1[lane];
#pragma unroll
    for (int f = 0; f < FF; ++f) {
        vhi = fmaf(xr[f], pW1[f * HH + lane], vhi);
        vhj = fmaf(xr[f], pW1[(FF + f) * HH + lane], vhj);
        v1  = fmaf(xr[f], bW1[f * HH + lane], v1);
    }
    v1 = fmaxf(v1, 0.f);

    // hb2 = relu(hb1 @ bW2 + bb2): broadcast hb1 across lanes via shuffles
    float v2 = bb2[lane];
#pragma unroll
    for (int k = 0; k < HH; ++k) {
        float hk = __shfl(v1, k);
        v2 = fmaf(hk, bW2[k * HH + lane], v2);
    }
    v2 = fmaxf(v2, 0.f);

    float bu = v2 * bW3[lane];
#pragma unroll
    for (int off = 32; off; off >>= 1) bu += __shfl_xor(bu, off);

    hi_p[row * HH + lane] = vhi;
    hj  [row * HH + lane] = vhj;
    if (lane == 0) base_u[row] = bu + bb3[0];

    // one block per b builds the compacted unmasked-j list
    if (a == 0) {
        int base0 = 0;
#pragma unroll
        for (int half = 0; half < 2; ++half) {
            int idx = half * 64 + lane;
            int m = mask[b * AA + idx];
            unsigned long long bal = __ballot(m != 0);
            int pos = __popcll(bal & ((1ull << lane) - 1ull));
            if (m) jlist[b * AA + base0 + pos] = idx;
            base0 += (int)__popcll(bal);
        }
        if (lane == 0) jcnt[b] = base0;
    }

    // one block transposes pair_W2 (columns contiguous)
    if (a == 1 && b == 0) {
#pragma unroll
        for (int n = 0; n < HH; ++n) W2t[n * HH + lane] = pW2[lane * HH + n];
    }
}

// ---------------- Kernel 2: pairwise MLP, lane = j ------------------------
// 4 waves/block (one i per wave). Weights in LDS (uniform-address ds_read =
// broadcast, conflict-free, off the scalar/VMEM pipes). h = 64 named floats,
// asm-pinned; __launch_bounds__(256,2) gives a 256-VGPR cap so the pinned
// values can neither be remat-reloaded (R2 failure) nor spilled (R3 failure).

#define REP16(M) M(0) M(1) M(2) M(3) M(4) M(5) M(6) M(7) \
                 M(8) M(9) M(10) M(11) M(12) M(13) M(14) M(15)

__global__ __launch_bounds__(256, 2)
void ddc_pairs(const float* __restrict__ hi_p, const float* __restrict__ hj,
               const float* __restrict__ base_u, const int* __restrict__ mask,
               const int* __restrict__ jlist, const int* __restrict__ jcnt,
               const float* __restrict__ W2t, const float* __restrict__ pb2,
               const float* __restrict__ pW3, const float* __restrict__ pb3,
               float* __restrict__ util) {
    __shared__ float sW[HH * HH];     // 16 KB, W2t row-major (row n = col n of W2)
    __shared__ float sb2[HH];
    __shared__ float sw3[HH];

    const int t = threadIdx.x;
    // cooperative stage: 256 threads x 4 float4 = 4096 floats
#pragma unroll
    for (int q = 0; q < 4; ++q)
        ((float4v*)sW)[q * 256 + t] = ((const float4v*)W2t)[q * 256 + t];
    if (t < HH) { sb2[t] = pb2[t]; sw3[t] = pW3[t]; }
    __syncthreads();

    const int wave = t >> 6;
    const int lane = t & 63;
    const int i = blockIdx.x * 4 + wave;
    const int b = blockIdx.y;
    if (mask[b * AA + i] == 0) return;   // masked row: softmax emits -1e9

    const float4v* __restrict__ hiPtr =
        (const float4v*)(hi_p + (b * AA + i) * HH);       // wave-uniform
    // hoist hi into loop-invariant named values (loaded once per i)
#define DECL_HI(q) const float4v hiv##q = hiPtr[q];
    REP16(DECL_HI)
#undef DECL_HI

    const int cnt = jcnt[b];
    const float b3v = pb3[0];

    float total = 0.f;
    for (int base = 0; base < cnt; base += 64) {
        const int jj = base + lane;
        const bool active = (jj < cnt);
        const int j = active ? jlist[b * AA + jj] : i;    // j==i path zeroed
        const float4v* __restrict__ hj4 =
            (const float4v*)(hj + (b * AA + j) * HH);     // per-lane row

        // h = relu(hi + hj): 64 named scalars, asm-pinned (no remat/spill
        // under the 256-VGPR cap)
#define DECL_H(q)                                                   \
        float h##q##x, h##q##y, h##q##z, h##q##w;                   \
        {   float4v v = hj4[q];                                     \
            h##q##x = fmaxf(hiv##q.x + v.x, 0.f);                   \
            h##q##y = fmaxf(hiv##q.y + v.y, 0.f);                   \
            h##q##z = fmaxf(hiv##q.z + v.z, 0.f);                   \
            h##q##w = fmaxf(hiv##q.w + v.w, 0.f);                   \
            asm volatile("" : "+v"(h##q##x), "+v"(h##q##y),         \
                              "+v"(h##q##z), "+v"(h##q##w)); }
        REP16(DECL_H)
#undef DECL_H

        float pe = b3v;
#pragma unroll 2
        for (int n = 0; n < HH; ++n) {
            const float4v* __restrict__ wrow =
                (const float4v*)(sW + n * HH);   // uniform addr -> broadcast
            float a0 = sb2[n], a1 = 0.f, a2 = 0.f, a3 = 0.f;
#define FMA_Q(q)                                                    \
            {   float4v w = wrow[q];                                \
                a0 = fmaf(h##q##x, w.x, a0);                        \
                a1 = fmaf(h##q##y, w.y, a1);                        \
                a2 = fmaf(h##q##z, w.z, a2);                        \
                a3 = fmaf(h##q##w, w.w, a3); }
            REP16(FMA_Q)
#undef FMA_Q
            const float acc = (a0 + a1) + (a2 + a3);
            pe = fmaf(fmaxf(acc, 0.f), sw3[n], pe);
        }
        if (!active || j == i) pe = 0.f;
        total += pe;
    }

#pragma unroll
    for (int off = 32; off; off >>= 1) total += __shfl_xor(total, off);
    if (lane == 0) util[b * AA + i] = base_u[b * AA + i] + total;
}

// ---------------- Kernel 3: per-b masked softmax over A=128 ---------------
__global__ __launch_bounds__(64)
void ddc_softmax(const float* __restrict__ util, const int* __restrict__ mask,
                 float* __restrict__ out) {
    const int b = blockIdx.x, lane = threadIdx.x;
    const int r0 = b * AA + lane, r1 = r0 + 64;
    const float u0 = (mask[r0] != 0) ? util[r0] : -1e9f;
    const float u1 = (mask[r1] != 0) ? util[r1] : -1e9f;

    float m = fmaxf(u0, u1);
#pragma unroll
    for (int off = 32; off; off >>= 1) m = fmaxf(m, __shfl_xor(m, off));

    const float e0 = __expf(u0 - m);
    const float e1 = __expf(u1 - m);
    float s = e0 + e1;
#pragma unroll
    for (int off = 32; off; off >>= 1) s += __shfl_xor(s, off);

    const float inv = 1.f / s;
    out[r0] = e0 * inv;
    out[r1] = e1 * inv;
}

extern "C" void kernel_launch(void* const* d_in, const int* in_sizes, int n_in,
                              void* d_out, int out_size, void* d_ws, size_t ws_size,
                              hipStream_t stream) {
    const float* X    = (const float*)d_in[0];
    const int*   mask = (const int*)  d_in[1];
    const float* bW1  = (const float*)d_in[2];
    const float* bb1  = (const float*)d_in[3];
    const float* bW2  = (const float*)d_in[4];
    const float* bb2  = (const float*)d_in[5];
    const float* bW3  = (const float*)d_in[6];
    const float* bb3  = (const float*)d_in[7];
    const float* pW1  = (const float*)d_in[8];
    const float* pb1  = (const float*)d_in[9];
    const float* pW2  = (const float*)d_in[10];
    const float* pb2  = (const float*)d_in[11];
    const float* pW3  = (const float*)d_in[12];
    const float* pb3  = (const float*)d_in[13];

    float* ws    = (float*)d_ws;
    float* hi_p  = ws + OFF_HIP;
    float* hjW   = ws + OFF_HJ;
    float* baseu = ws + OFF_BU;
    float* util  = ws + OFF_UTIL;
    float* W2t   = ws + OFF_W2T;
    int*   jlist = (int*)(ws + OFF_JLIST);
    int*   jcnt  = (int*)(ws + OFF_JCNT);

    float* out = (float*)d_out;

    dim3 g1(AA, BB);
    ddc_features<<<g1, 64, 0, stream>>>(X, mask, bW1, bb1, bW2, bb2, bW3, bb3,
                                        pW1, pb1, pW2,
                                        hi_p, hjW, baseu, W2t, jlist, jcnt);
    dim3 g2(AA / 4, BB);
    ddc_pairs<<<g2, 256, 0, stream>>>(hi_p, hjW, baseu, mask, jlist, jcnt,
                                      W2t, pb2, pW3, pb3, util);
    ddc_softmax<<<BB, 64, 0, stream>>>(util, mask, out);
}

// Round 6
// 69.916 us; speedup vs baseline: 2.4955x; 2.4955x over previous
//
#include <hip/hip_runtime.h>
#include <hip/hip_bf16.h>

// Sizes (fixed by the reference)
#define BB 64
#define AA 128
#define FF 32
#define HH 64

typedef float  f32x4  __attribute__((ext_vector_type(4)));
typedef float  f32x16 __attribute__((ext_vector_type(16)));
typedef __bf16 bf16x8 __attribute__((ext_vector_type(8)));

// ws layout (float offsets)
#define OFF_HIP   0          // hi_p fp32 [B*A][64]  (pair_b1 folded in)
#define OFF_HJ    524288     // hj   fp32 [B*A][64]
#define OFF_BU    1048576    // base_u [B*A]
#define OFF_UTIL  1056768    // util [B*A]
#define OFF_W2HI  1064960    // W2 split hi: bf16 bits [n=64][k=64] (k-contig) = 2048 floats
#define OFF_W2LO  1067008    // W2 split lo

static __device__ __forceinline__ unsigned short f2b(float x) {
    __hip_bfloat16 h = __float2bfloat16(x);
    return __builtin_bit_cast(unsigned short, h);
}
static __device__ __forceinline__ float b2f(unsigned short u) {
    unsigned v = ((unsigned)u) << 16;
    return __builtin_bit_cast(float, v);
}

// ---------------- Kernel 1: per-(b,a) features + W2 bf16-split ------------
__global__ __launch_bounds__(64)
void ddc_features(const float* __restrict__ X, const int* __restrict__ mask,
                  const float* __restrict__ bW1, const float* __restrict__ bb1,
                  const float* __restrict__ bW2, const float* __restrict__ bb2,
                  const float* __restrict__ bW3, const float* __restrict__ bb3,
                  const float* __restrict__ pW1, const float* __restrict__ pb1,
                  const float* __restrict__ pW2,
                  float* __restrict__ hi_p, float* __restrict__ hj,
                  float* __restrict__ base_u,
                  unsigned short* __restrict__ W2hi,
                  unsigned short* __restrict__ W2lo) {
    const int a = blockIdx.x, b = blockIdx.y, lane = threadIdx.x;
    const int row = b * AA + a;

    // X row is wave-uniform -> scalar loads
    const float* __restrict__ x = X + row * FF;
    float xr[FF];
#pragma unroll
    for (int f = 0; f < FF; ++f) xr[f] = x[f];

    float vhi = pb1[lane];      // fold pair_b1 into hi
    float vhj = 0.f;
    float v1  = bb1[lane];
#pragma unroll
    for (int f = 0; f < FF; ++f) {
        vhi = fmaf(xr[f], pW1[f * HH + lane], vhi);
        vhj = fmaf(xr[f], pW1[(FF + f) * HH + lane], vhj);
        v1  = fmaf(xr[f], bW1[f * HH + lane], v1);
    }
    v1 = fmaxf(v1, 0.f);

    // hb2 = relu(hb1 @ bW2 + bb2): broadcast hb1 across lanes via shuffles
    float v2 = bb2[lane];
#pragma unroll
    for (int k = 0; k < HH; ++k) {
        float hk = __shfl(v1, k);
        v2 = fmaf(hk, bW2[k * HH + lane], v2);
    }
    v2 = fmaxf(v2, 0.f);

    float bu = v2 * bW3[lane];
#pragma unroll
    for (int off = 32; off; off >>= 1) bu += __shfl_xor(bu, off);

    hi_p[row * HH + lane] = vhi;
    hj  [row * HH + lane] = vhj;
    if (lane == 0) base_u[row] = bu + bb3[0];

    // one block splits pair_W2 into bf16 hi/lo, stored [n][k] (k-contig)
    if (a == 1 && b == 0) {
        const int n = lane;
        for (int k = 0; k < HH; ++k) {
            float w = pW2[k * HH + n];
            unsigned short uh = f2b(w);
            W2hi[n * HH + k] = uh;
            W2lo[n * HH + k] = f2b(w - b2f(uh));
        }
    }
}

// ---------------- Kernel 2: pairwise MLP via split-bf16 MFMA --------------
// One wave per (b,i). Per i: P[j,n] = h(i,j) @ W2 as a 128x64x64 GEMM using
// mfma_f32_32x32x16_bf16 with 3-term bf16 hi/lo split (fp32-class accuracy).
// A-frag: row j = lane&31, k = (lane>>5)*8+e.  B-frag: col n = lane&31, same k.
// C: col = lane&31, row = (reg&3)+8*(reg>>2)+4*(lane>>5).
// Epilogue: pe-partials masked (mf[j], j!=i) and FMA'd into one scalar,
// single 64-lane butterfly at the end.
__global__ __launch_bounds__(256, 2)
void ddc_pairs_mfma(const float* __restrict__ hi_p, const float* __restrict__ hj,
                    const float* __restrict__ base_u, const int* __restrict__ mask,
                    const unsigned short* __restrict__ W2hi,
                    const unsigned short* __restrict__ W2lo,
                    const float* __restrict__ pb2, const float* __restrict__ pW3,
                    const float* __restrict__ pb3, float* __restrict__ util) {
    __shared__ float sHJ[AA][HH + 4];   // 34816 B, +4 pad -> conflict-light
    __shared__ float sHI[4][HH + 4];
    __shared__ float sMF[AA];

    const int t = threadIdx.x;
    const int b = blockIdx.y;

    // stage hj rows for this b: thread t copies 32 floats of row t>>1
    {
        const int r = t >> 1, hf = t & 1;
        const f32x4* __restrict__ src =
            (const f32x4*)(hj + (b * AA + r) * HH + hf * 32);
        f32x4* dst = (f32x4*)&sHJ[r][hf * 32];
#pragma unroll
        for (int q = 0; q < 8; ++q) dst[q] = src[q];
    }
    if (t < 64) {       // 4 i-rows x 16 threads
        const int il = t >> 4, q = t & 15;
        const int ii = blockIdx.x * 4 + il;
        ((f32x4*)&sHI[il][0])[q] = ((const f32x4*)(hi_p + (b * AA + ii) * HH))[q];
    }
    if (t >= 128) sMF[t - 128] = mask[b * AA + (t - 128)] ? 1.f : 0.f;
    __syncthreads();

    const int w = t >> 6, l = t & 63;
    const int i = blockIdx.x * 4 + w;
    if (mask[b * AA + i] == 0) return;   // masked i: softmax emits -1e9

    const int col = l & 31, half = l >> 5;

    // B-fragments (loop-invariant): [nt][ks] hi/lo, 16 x 4 VGPRs
    bf16x8 Bh[2][4], Bl[2][4];
#pragma unroll
    for (int nt = 0; nt < 2; ++nt)
#pragma unroll
        for (int ks = 0; ks < 4; ++ks) {
            const int n = nt * 32 + col, ko = ks * 16 + half * 8;
            Bh[nt][ks] = *(const bf16x8*)(W2hi + n * HH + ko);
            Bl[nt][ks] = *(const bf16x8*)(W2lo + n * HH + ko);
        }
    const float b2v0 = pb2[col], b2v1 = pb2[32 + col];
    const float w3v0 = pW3[col], w3v1 = pW3[32 + col];
    const float b3s  = pb3[0] * (1.f / 32.f);   // b3 spread over 32 col-lanes

    // hi row slice for this lane's k-chunks (32 floats), LDS -> regs once
    f32x4 yv[8];
#pragma unroll
    for (int q = 0; q < 8; ++q)
        yv[q] = *(const f32x4*)&sHI[w][(q >> 1) * 16 + half * 8 + (q & 1) * 4];

    float tsum = 0.f;
#pragma unroll
    for (int jt = 0; jt < 4; ++jt) {
        f32x16 acc0 = 0.f, acc1 = 0.f;
        const int jj = jt * 32 + col;
#pragma unroll
        for (int ks = 0; ks < 4; ++ks) {
            const int ko = ks * 16 + half * 8;
            f32x4 x0 = *(const f32x4*)&sHJ[jj][ko];
            f32x4 x1 = *(const f32x4*)&sHJ[jj][ko + 4];
            f32x4 y0 = yv[ks * 2], y1 = yv[ks * 2 + 1];
            bf16x8 ah, al;
#pragma unroll
            for (int e = 0; e < 4; ++e) {
                float h0 = fmaxf(x0[e] + y0[e], 0.f);
                float h1 = fmaxf(x1[e] + y1[e], 0.f);
                unsigned short u0 = f2b(h0), u1 = f2b(h1);
                ah[e]     = __builtin_bit_cast(__bf16, u0);
                ah[4 + e] = __builtin_bit_cast(__bf16, u1);
                al[e]     = __builtin_bit_cast(__bf16, f2b(h0 - b2f(u0)));
                al[4 + e] = __builtin_bit_cast(__bf16, f2b(h1 - b2f(u1)));
            }
            acc0 = __builtin_amdgcn_mfma_f32_32x32x16_bf16(al, Bh[0][ks], acc0, 0, 0, 0);
            acc0 = __builtin_amdgcn_mfma_f32_32x32x16_bf16(ah, Bl[0][ks], acc0, 0, 0, 0);
            acc0 = __builtin_amdgcn_mfma_f32_32x32x16_bf16(ah, Bh[0][ks], acc0, 0, 0, 0);
            acc1 = __builtin_amdgcn_mfma_f32_32x32x16_bf16(al, Bh[1][ks], acc1, 0, 0, 0);
            acc1 = __builtin_amdgcn_mfma_f32_32x32x16_bf16(ah, Bl[1][ks], acc1, 0, 0, 0);
            acc1 = __builtin_amdgcn_mfma_f32_32x32x16_bf16(ah, Bh[1][ks], acc1, 0, 0, 0);
        }
        // epilogue for this j-tile: mask + W3 contraction, no per-row reduce
#pragma unroll
        for (int r = 0; r < 16; ++r) {
            const int rrow = (r & 3) + 8 * (r >> 2) + 4 * half;
            const int j = jt * 32 + rrow;
            float v = fmaxf(acc0[r] + b2v0, 0.f) * w3v0 +
                      fmaxf(acc1[r] + b2v1, 0.f) * w3v1 + b3s;
            float mf = (j == i) ? 0.f : sMF[j];
            tsum = fmaf(v, mf, tsum);
        }
    }
#pragma unroll
    for (int off = 32; off; off >>= 1) tsum += __shfl_xor(tsum, off);
    if (l == 0) util[b * AA + i] = base_u[b * AA + i] + tsum;
}

// ---------------- Kernel 3: per-b masked softmax over A=128 ---------------
__global__ __launch_bounds__(64)
void ddc_softmax(const float* __restrict__ util, const int* __restrict__ mask,
                 float* __restrict__ out) {
    const int b = blockIdx.x, lane = threadIdx.x;
    const int r0 = b * AA + lane, r1 = r0 + 64;
    const float u0 = (mask[r0] != 0) ? util[r0] : -1e9f;
    const float u1 = (mask[r1] != 0) ? util[r1] : -1e9f;

    float m = fmaxf(u0, u1);
#pragma unroll
    for (int off = 32; off; off >>= 1) m = fmaxf(m, __shfl_xor(m, off));

    const float e0 = __expf(u0 - m);
    const float e1 = __expf(u1 - m);
    float s = e0 + e1;
#pragma unroll
    for (int off = 32; off; off >>= 1) s += __shfl_xor(s, off);

    const float inv = 1.f / s;
    out[r0] = e0 * inv;
    out[r1] = e1 * inv;
}

extern "C" void kernel_launch(void* const* d_in, const int* in_sizes, int n_in,
                              void* d_out, int out_size, void* d_ws, size_t ws_size,
                              hipStream_t stream) {
    const float* X    = (const float*)d_in[0];
    const int*   mask = (const int*)  d_in[1];
    const float* bW1  = (const float*)d_in[2];
    const float* bb1  = (const float*)d_in[3];
    const float* bW2  = (const float*)d_in[4];
    const float* bb2  = (const float*)d_in[5];
    const float* bW3  = (const float*)d_in[6];
    const float* bb3  = (const float*)d_in[7];
    const float* pW1  = (const float*)d_in[8];
    const float* pb1  = (const float*)d_in[9];
    const float* pW2  = (const float*)d_in[10];
    const float* pb2  = (const float*)d_in[11];
    const float* pW3  = (const float*)d_in[12];
    const float* pb3  = (const float*)d_in[13];

    float* ws    = (float*)d_ws;
    float* hi_p  = ws + OFF_HIP;
    float* hjW   = ws + OFF_HJ;
    float* baseu = ws + OFF_BU;
    float* util  = ws + OFF_UTIL;
    unsigned short* W2hi = (unsigned short*)(ws + OFF_W2HI);
    unsigned short* W2lo = (unsigned short*)(ws + OFF_W2LO);

    float* out = (float*)d_out;

    dim3 g1(AA, BB);
    ddc_features<<<g1, 64, 0, stream>>>(X, mask, bW1, bb1, bW2, bb2, bW3, bb3,
                                        pW1, pb1, pW2,
                                        hi_p, hjW, baseu, W2hi, W2lo);
    dim3 g2(AA / 4, BB);
    ddc_pairs_mfma<<<g2, 256, 0, stream>>>(hi_p, hjW, baseu, mask, W2hi, W2lo,
                                           pb2, pW3, pb3, util);
    ddc_softmax<<<BB, 64, 0, stream>>>(util, mask, out);
}